// Round 1
// baseline (522.480 us; speedup 1.0000x reference)
//
#include <hip/hip_runtime.h>

#define BLOCKS 2048
#define TPB 256

// Main pass: per-row hamming-distance histogram + per-column BCE loss sums.
// One wave handles 4 rows (256 floats) per iteration: lane k does the k-th
// float4 load of the chunk -> 16B/lane coalesced. Row = k>>4, cols = 4*(k&15)+t.
__global__ __launch_bounds__(TPB) void hwbce_main(
    const float4* __restrict__ pred, const float4* __restrict__ gt,
    unsigned int* __restrict__ g_hist, float* __restrict__ g_col, int nchunks)
{
    __shared__ unsigned int lhist[64];
    __shared__ float lcol[64];
    const int tid = threadIdx.x;
    if (tid < 64) { lhist[tid] = 0u; lcol[tid] = 0.0f; }
    __syncthreads();

    const int lane  = tid & 63;
    const int wid   = tid >> 6;                     // wave in block (0..3)
    const int gwave = blockIdx.x * (TPB / 64) + wid;
    const int nwav  = gridDim.x * (TPB / 64);
    const int sub   = lane & 15;                    // column group within row

    const float C0 = 0.69314718055994531f;          // ln 2           (x==0 case)
    const float C1 = 0.31326168751822287f;          // log1p(e^-1)    (x==1 base)

    float a0 = 0.f, a1 = 0.f, a2 = 0.f, a3 = 0.f;

    for (int chunk = gwave; chunk < nchunks; chunk += nwav) {
        const int idx = chunk * 64 + lane;          // float4 index
        const float4 p = pred[idx];
        const float4 g = gt[idx];

        // hamming diff count for this lane's 4 elements (raw != compare)
        int d = (p.x != g.x) + (p.y != g.y) + (p.z != g.z) + (p.w != g.w);

        // BCE(x=round(p), y=g): (1-x)*ln2 + x*((1-y) + log1p(e^-1))
        float x;
        x = rintf(p.x); a0 += (1.f - x) * C0 + x * ((1.f - g.x) + C1);
        x = rintf(p.y); a1 += (1.f - x) * C0 + x * ((1.f - g.y) + C1);
        x = rintf(p.z); a2 += (1.f - x) * C0 + x * ((1.f - g.z) + C1);
        x = rintf(p.w); a3 += (1.f - x) * C0 + x * ((1.f - g.w) + C1);

        // reduce d over the 16-lane subgroup owning this row
        d += __shfl_xor(d, 1);
        d += __shfl_xor(d, 2);
        d += __shfl_xor(d, 4);
        d += __shfl_xor(d, 8);
        if (sub == 0) {
            atomicAdd(&lhist[d < 63 ? d : 63], 1u);  // histc: value==max -> last bin
        }
    }

    // per-column loss partials -> LDS
    const int col = sub * 4;
    atomicAdd(&lcol[col + 0], a0);
    atomicAdd(&lcol[col + 1], a1);
    atomicAdd(&lcol[col + 2], a2);
    atomicAdd(&lcol[col + 3], a3);

    __syncthreads();
    if (tid < 64) {
        if (lhist[tid]) atomicAdd(&g_hist[tid], lhist[tid]);
        atomicAdd(&g_col[tid], lcol[tid]);
    }
}

// Finalize: weights from histogram, weighted sum of column sums, mean.
__global__ void hwbce_final(const unsigned int* __restrict__ g_hist,
                            const float* __restrict__ g_col,
                            float* __restrict__ out, float inv_total)
{
    const int j = threadIdx.x;                      // 64 threads
    const float h = (float)g_hist[j];
    const float w = expf(3.0f * fminf(h, 0.51f - h));
    float v = w * g_col[j];
    v += __shfl_xor(v, 32);
    v += __shfl_xor(v, 16);
    v += __shfl_xor(v, 8);
    v += __shfl_xor(v, 4);
    v += __shfl_xor(v, 2);
    v += __shfl_xor(v, 1);
    if (j == 0) out[0] = v * inv_total;
}

extern "C" void kernel_launch(void* const* d_in, const int* in_sizes, int n_in,
                              void* d_out, int out_size, void* d_ws, size_t ws_size,
                              hipStream_t stream)
{
    const float4* pred = (const float4*)d_in[0];
    const float4* gt   = (const float4*)d_in[1];
    float* out = (float*)d_out;

    unsigned int* g_hist = (unsigned int*)d_ws;
    float* g_col = (float*)((char*)d_ws + 64 * sizeof(unsigned int));

    const long total  = (long)in_sizes[0];          // N * 64
    const int  nrows  = (int)(total / 64);
    const int  nchunks = nrows / 4;                 // 4 rows per wave-iteration

    hipMemsetAsync(d_ws, 0, 64 * (sizeof(unsigned int) + sizeof(float)), stream);
    hwbce_main<<<BLOCKS, TPB, 0, stream>>>(pred, gt, g_hist, g_col, nchunks);
    hwbce_final<<<1, 64, 0, stream>>>(g_hist, g_col, out, 1.0f / (float)total);
}

// Round 2
// 513.275 us; speedup vs baseline: 1.0179x; 1.0179x over previous
//
#include <hip/hip_runtime.h>

#define BLOCKS 2048
#define TPB 256

// Main pass: per-row hamming-distance histogram + per-column BCE partial sums.
// One wave handles 4 rows (256 floats) per chunk: lane k does the k-th
// dwordx4 load -> 16B/lane coalesced. Row-in-chunk = lane>>4, cols = 4*(lane&15)+t.
//
// Cross-lane trick: the per-element (p != g) compares double as wave ballots.
// Row hamming distance = popcount of the 16-bit slice of each ballot mask
// belonging to that row's 16-lane subgroup -> no ds_swizzle chain.
//
// BCE on exact {0,1} inputs: loss = ln2 + p*((1-g) + log1p(e^-1) - ln2).
// The ln2 constant is hoisted (adds N*ln2 per column at finalize), leaving
// one v_sub + one v_fma per element in the hot loop.
__global__ __launch_bounds__(TPB) void hwbce_main(
    const float4* __restrict__ pred, const float4* __restrict__ gt,
    unsigned int* __restrict__ g_hist, float* __restrict__ g_col, int nchunks)
{
    __shared__ unsigned int lhist[64];
    __shared__ float lcol[64];
    const int tid = threadIdx.x;
    if (tid < 64) { lhist[tid] = 0u; lcol[tid] = 0.0f; }
    __syncthreads();

    const int lane  = tid & 63;
    const int wid   = tid >> 6;
    const int gwave = blockIdx.x * (TPB / 64) + wid;
    const int nwav  = gridDim.x * (TPB / 64);
    const int sub   = lane & 15;
    const unsigned long long gm = 0xFFFFull << ((lane >> 4) << 4); // this row's 16-lane slice

    // K1 = 1 + log1p(e^-1) - ln2
    const float K1 = 0.62011450695827756f;

    float a0 = 0.f, a1 = 0.f, a2 = 0.f, a3 = 0.f;

    for (int chunk = gwave; chunk < nchunks; chunk += 2 * nwav) {
        const int idx0 = chunk * 64 + lane;
        const float4 p0 = pred[idx0];
        const float4 g0 = gt[idx0];
        const int chunk1 = chunk + nwav;
        float4 p1, g1;
        if (chunk1 < nchunks) {
            const int idx1 = chunk1 * 64 + lane;
            p1 = pred[idx1];
            g1 = gt[idx1];
        }

        // --- chunk 0 ---
        unsigned long long bx = __ballot(p0.x != g0.x);
        unsigned long long by = __ballot(p0.y != g0.y);
        unsigned long long bz = __ballot(p0.z != g0.z);
        unsigned long long bw = __ballot(p0.w != g0.w);
        a0 = fmaf(p0.x, K1 - g0.x, a0);
        a1 = fmaf(p0.y, K1 - g0.y, a1);
        a2 = fmaf(p0.z, K1 - g0.z, a2);
        a3 = fmaf(p0.w, K1 - g0.w, a3);
        if (sub == 0) {
            int d = __popcll(bx & gm) + __popcll(by & gm)
                  + __popcll(bz & gm) + __popcll(bw & gm);
            atomicAdd(&lhist[d < 63 ? d : 63], 1u);
        }

        // --- chunk 1 ---
        if (chunk1 < nchunks) {
            bx = __ballot(p1.x != g1.x);
            by = __ballot(p1.y != g1.y);
            bz = __ballot(p1.z != g1.z);
            bw = __ballot(p1.w != g1.w);
            a0 = fmaf(p1.x, K1 - g1.x, a0);
            a1 = fmaf(p1.y, K1 - g1.y, a1);
            a2 = fmaf(p1.z, K1 - g1.z, a2);
            a3 = fmaf(p1.w, K1 - g1.w, a3);
            if (sub == 0) {
                int d = __popcll(bx & gm) + __popcll(by & gm)
                      + __popcll(bz & gm) + __popcll(bw & gm);
                atomicAdd(&lhist[d < 63 ? d : 63], 1u);
            }
        }
    }

    const int col = sub * 4;
    atomicAdd(&lcol[col + 0], a0);
    atomicAdd(&lcol[col + 1], a1);
    atomicAdd(&lcol[col + 2], a2);
    atomicAdd(&lcol[col + 3], a3);

    __syncthreads();
    if (tid < 64) {
        if (lhist[tid]) atomicAdd(&g_hist[tid], lhist[tid]);
        atomicAdd(&g_col[tid], lcol[tid]);
    }
}

// Finalize: weights from histogram, weighted sum of (column sums + N*ln2), mean.
__global__ void hwbce_final(const unsigned int* __restrict__ g_hist,
                            const float* __restrict__ g_col,
                            float* __restrict__ out,
                            float n_ln2, float inv_total)
{
    __shared__ double partial[64];
    const int j = threadIdx.x;                      // 64 threads
    const float h = (float)g_hist[j];
    const float w = expf(3.0f * fminf(h, 0.51f - h));
    partial[j] = (double)w * ((double)g_col[j] + (double)n_ln2);
    __syncthreads();
    if (j == 0) {
        double s = 0.0;
        #pragma unroll
        for (int k = 0; k < 64; ++k) s += partial[k];
        out[0] = (float)(s * (double)inv_total);
    }
}

extern "C" void kernel_launch(void* const* d_in, const int* in_sizes, int n_in,
                              void* d_out, int out_size, void* d_ws, size_t ws_size,
                              hipStream_t stream)
{
    const float4* pred = (const float4*)d_in[0];
    const float4* gt   = (const float4*)d_in[1];
    float* out = (float*)d_out;

    unsigned int* g_hist = (unsigned int*)d_ws;
    float* g_col = (float*)((char*)d_ws + 64 * sizeof(unsigned int));

    const long total   = (long)in_sizes[0];         // N * 64
    const long nrows   = total / 64;
    const int  nchunks = (int)(nrows / 4);          // 4 rows per wave-iteration

    const float n_ln2 = (float)((double)nrows * 0.69314718055994530942);

    hipMemsetAsync(d_ws, 0, 64 * (sizeof(unsigned int) + sizeof(float)), stream);
    hwbce_main<<<BLOCKS, TPB, 0, stream>>>(pred, gt, g_hist, g_col, nchunks);
    hwbce_final<<<1, 64, 0, stream>>>(g_hist, g_col, out, n_ln2, 1.0f / (float)total);
}

// Round 3
// 503.627 us; speedup vs baseline: 1.0374x; 1.0192x over previous
//
#include <hip/hip_runtime.h>

#define BLOCKS 2048
#define TPB 256

// Main pass: per-row hamming-distance histogram + per-column BCE partial sums.
// One wave handles a SUPERCHUNK = 16 rows = 1024 floats = 4KB per array per
// iteration: 8 dwordx4 wave-loads issued back-to-back (8KB in flight per wave)
// before any use, so the compiler drains vmcnt incrementally while processing.
//
// Per 4-row chunk: lane k holds floats [4*(k&15) .. +3] of row (k>>4).
// (p != g) compares double as wave ballots; row hamming distance = popcount of
// the row's 16-bit slice of the 4 ballot masks -> no cross-lane data movement.
//
// BCE on exact {0,1} inputs: loss = ln2 + p*((1-g) + log1p(e^-1) - ln2).
// ln2*N is added per column at finalize; hot loop is one v_sub + v_fma per elem.
__global__ __launch_bounds__(TPB) void hwbce_main(
    const float4* __restrict__ pred, const float4* __restrict__ gt,
    unsigned int* __restrict__ g_hist, float* __restrict__ g_col,
    int nsuper, int nchunks)
{
    __shared__ unsigned int lhist[64];
    __shared__ float lcol[64];
    const int tid = threadIdx.x;
    if (tid < 64) { lhist[tid] = 0u; lcol[tid] = 0.0f; }
    __syncthreads();

    const int lane  = tid & 63;
    const int wid   = tid >> 6;
    const int gwave = blockIdx.x * (TPB / 64) + wid;
    const int nwav  = gridDim.x * (TPB / 64);
    const int sub   = lane & 15;
    const unsigned long long gm = 0xFFFFull << ((lane >> 4) << 4);

    const float K1 = 0.62011450695827756f;   // 1 + log1p(e^-1) - ln2

    float a0 = 0.f, a1 = 0.f, a2 = 0.f, a3 = 0.f;

#define PROC(P, G)                                                          \
    do {                                                                    \
        unsigned long long bx = __ballot((P).x != (G).x);                   \
        unsigned long long by = __ballot((P).y != (G).y);                   \
        unsigned long long bz = __ballot((P).z != (G).z);                   \
        unsigned long long bw = __ballot((P).w != (G).w);                   \
        a0 = fmaf((P).x, K1 - (G).x, a0);                                   \
        a1 = fmaf((P).y, K1 - (G).y, a1);                                   \
        a2 = fmaf((P).z, K1 - (G).z, a2);                                   \
        a3 = fmaf((P).w, K1 - (G).w, a3);                                   \
        if (sub == 0) {                                                     \
            int d = __popcll(bx & gm) + __popcll(by & gm)                   \
                  + __popcll(bz & gm) + __popcll(bw & gm);                  \
            atomicAdd(&lhist[d < 63 ? d : 63], 1u);                        \
        }                                                                   \
    } while (0)

    // Superchunk loop: 4 contiguous chunks (16 rows), 8 loads in flight.
    for (int s = gwave; s < nsuper; s += nwav) {
        const int base = s * 256 + lane;            // float4 index
        const float4 p0 = pred[base      ];
        const float4 g0 = gt  [base      ];
        const float4 p1 = pred[base +  64];
        const float4 g1 = gt  [base +  64];
        const float4 p2 = pred[base + 128];
        const float4 g2 = gt  [base + 128];
        const float4 p3 = pred[base + 192];
        const float4 g3 = gt  [base + 192];
        PROC(p0, g0);
        PROC(p1, g1);
        PROC(p2, g2);
        PROC(p3, g3);
    }

    // Tail: leftover chunks not covered by full superchunks (usually none).
    for (int c = nsuper * 4 + gwave; c < nchunks; c += nwav) {
        const int idx = c * 64 + lane;
        const float4 p = pred[idx];
        const float4 g = gt[idx];
        PROC(p, g);
    }
#undef PROC

    const int col = sub * 4;
    atomicAdd(&lcol[col + 0], a0);
    atomicAdd(&lcol[col + 1], a1);
    atomicAdd(&lcol[col + 2], a2);
    atomicAdd(&lcol[col + 3], a3);

    __syncthreads();
    if (tid < 64) {
        if (lhist[tid]) atomicAdd(&g_hist[tid], lhist[tid]);
        atomicAdd(&g_col[tid], lcol[tid]);
    }
}

// Finalize: weights from histogram, weighted sum of (column sums + N*ln2), mean.
__global__ void hwbce_final(const unsigned int* __restrict__ g_hist,
                            const float* __restrict__ g_col,
                            float* __restrict__ out,
                            float n_ln2, float inv_total)
{
    __shared__ double partial[64];
    const int j = threadIdx.x;                      // 64 threads
    const float h = (float)g_hist[j];
    const float w = expf(3.0f * fminf(h, 0.51f - h));
    partial[j] = (double)w * ((double)g_col[j] + (double)n_ln2);
    __syncthreads();
    if (j == 0) {
        double s = 0.0;
        #pragma unroll
        for (int k = 0; k < 64; ++k) s += partial[k];
        out[0] = (float)(s * (double)inv_total);
    }
}

extern "C" void kernel_launch(void* const* d_in, const int* in_sizes, int n_in,
                              void* d_out, int out_size, void* d_ws, size_t ws_size,
                              hipStream_t stream)
{
    const float4* pred = (const float4*)d_in[0];
    const float4* gt   = (const float4*)d_in[1];
    float* out = (float*)d_out;

    unsigned int* g_hist = (unsigned int*)d_ws;
    float* g_col = (float*)((char*)d_ws + 64 * sizeof(unsigned int));

    const long total   = (long)in_sizes[0];         // N * 64
    const long nrows   = total / 64;
    const int  nchunks = (int)(nrows / 4);          // 4 rows per chunk
    const int  nsuper  = nchunks / 4;               // 16 rows per superchunk

    const float n_ln2 = (float)((double)nrows * 0.69314718055994530942);

    hipMemsetAsync(d_ws, 0, 64 * (sizeof(unsigned int) + sizeof(float)), stream);
    hwbce_main<<<BLOCKS, TPB, 0, stream>>>(pred, gt, g_hist, g_col, nsuper, nchunks);
    hwbce_final<<<1, 64, 0, stream>>>(g_hist, g_col, out, n_ln2, 1.0f / (float)total);
}